// Round 5
// baseline (1487.745 us; speedup 1.0000x reference)
//
#include <hip/hip_runtime.h>
#include <hip/hip_bf16.h>

#define N_NODES 50000
#define N_EDGES 800000
#define N_GRAPHS 500
#define IN_DIM 128
#define HID 64
#define OUT_DIM 10
#define NB_BUCK ((N_NODES + 63) >> 6)  // 782 buckets of 64 nodes

// ---------------- zero ----------------
__global__ void zero_i_kernel(int* __restrict__ p, int n) {
    int i = blockIdx.x * blockDim.x + threadIdx.x;
    if (i < n) p[i] = 0;
}

// ---------------- degree histogram ----------------
__global__ void hist_kernel(const int* __restrict__ dst, int* __restrict__ cnt, int e) {
    int i = blockIdx.x * blockDim.x + threadIdx.x;
    if (i < e) atomicAdd(&cnt[dst[i]], 1);
}

// ---------------- per-bucket degree sum + dinv ----------------
__global__ void bsum_dinv_kernel(const int* __restrict__ cnt, float* __restrict__ dinv,
                                 int* __restrict__ bsum, int n) {
    int b = blockIdx.x;
    int lane = threadIdx.x;  // 64
    int i = b * 64 + lane;
    int c = (i < n) ? cnt[i] : 0;
    if (i < n) dinv[i] = rsqrtf((float)(c + 1));
    int v = c;
    for (int off = 32; off; off >>= 1) v += __shfl_down(v, off);
    if (lane == 0) bsum[b] = v;
}

// ---------------- exclusive scan over NB_BUCK bucket sums (single block) ----------------
__global__ void bscan_kernel(const int* __restrict__ bsum, int* __restrict__ bstart,
                             int* __restrict__ bcursor, int nb, int e) {
    __shared__ int s[1024];
    int t = threadIdx.x;
    int v = (t < nb) ? bsum[t] : 0;
    s[t] = v;
    __syncthreads();
    for (int off = 1; off < 1024; off <<= 1) {
        int x = (t >= off) ? s[t - off] : 0;
        __syncthreads();
        s[t] += x;
        __syncthreads();
    }
    int excl = s[t] - v;
    if (t < nb) {
        bstart[t] = excl;
        bcursor[t] = excl;
    }
    if (t == 0) bstart[nb] = e;
}

// ---------------- bucket fill: packed (dlocal<<16 | src), adjacent slots per bucket ----------------
__global__ void bfill_kernel(const int* __restrict__ src, const int* __restrict__ dst,
                             int* __restrict__ bcursor, unsigned* __restrict__ pairs, int e) {
    int i = blockIdx.x * blockDim.x + threadIdx.x;
    if (i < e) {
        int d = dst[i];
        int slot = atomicAdd(&bcursor[d >> 6], 1);
        pairs[slot] = ((unsigned)(d & 63) << 16) | (unsigned)src[i];
    }
}

// ---------------- linear (+ dinv pre-scale): C[r,f] = dinv[r]*sum_k A[r,k]*W[k,f] ----------------
// 256 threads, 64-row tile, 4x4 micro-tile. W in LDS; A streamed from global.
template <int K>
__global__ __launch_bounds__(256) void linear_kernel(
    const float* __restrict__ A, const float* __restrict__ W,
    const float* __restrict__ dinv, float* __restrict__ C, int n) {
    __shared__ float Ws[K][64];
    int tid = threadIdx.x;
    int tx = tid & 15;   // feat group (4 feats)
    int ty = tid >> 4;   // row group (4 rows)
    {
        const float4* Wv = (const float4*)W;
        float4* Wsv = (float4*)&Ws[0][0];
        for (int i = tid; i < K * 16; i += 256) Wsv[i] = Wv[i];
    }
    __syncthreads();
    int r0 = blockIdx.x * 64 + ty * 4;
    float acc[4][4] = {};
    for (int k = 0; k < K; k += 4) {
        float4 w[4];
#pragma unroll
        for (int kk = 0; kk < 4; ++kk) w[kk] = *(const float4*)&Ws[k + kk][tx * 4];
#pragma unroll
        for (int i = 0; i < 4; ++i) {
            int r = r0 + i;
            if (r >= n) r = n - 1;  // clamped load; store is guarded
            float4 a = *(const float4*)&A[(size_t)r * K + k];
            float av[4] = {a.x, a.y, a.z, a.w};
#pragma unroll
            for (int kk = 0; kk < 4; ++kk) {
                acc[i][0] += av[kk] * w[kk].x;
                acc[i][1] += av[kk] * w[kk].y;
                acc[i][2] += av[kk] * w[kk].z;
                acc[i][3] += av[kk] * w[kk].w;
            }
        }
    }
#pragma unroll
    for (int i = 0; i < 4; ++i) {
        int r = r0 + i;
        if (r < n) {
            float s = dinv[r];
            float4 v = {acc[i][0] * s, acc[i][1] * s, acc[i][2] * s, acc[i][3] * s};
            *(float4*)&C[(size_t)r * 64 + tx * 4] = v;
        }
    }
}

// ---------------- bucketed gather: LDS accumulator per 64-node bucket ----------------
// out[d,f] = relu( dinv[d] * ( hs[d,f] + sum_{s in N(d)} hs[s,f] ) + b[f] )
__global__ __launch_bounds__(256) void gather_bucket_kernel(
    const float* __restrict__ hs, const unsigned* __restrict__ pairs,
    const int* __restrict__ bstart, const float* __restrict__ dinv,
    const float* __restrict__ bias, float* __restrict__ outp, int n) {
    __shared__ float acc[64 * 64];  // 16 KB; bank = f%32 -> 2 lanes/bank (free)
    int tid = threadIdx.x;
    int b = blockIdx.x;
    int f = tid & 63;
    int wave = tid >> 6;  // 4 waves
    int node0 = b * 64;

    // init accumulator with self-loop rows (hs already dinv-prescaled)
    for (int idx4 = tid; idx4 < 64 * 16; idx4 += 256) {
        int r = idx4 >> 4, c4 = (idx4 & 15) * 4;
        int node = node0 + r;
        float4 v = {0.f, 0.f, 0.f, 0.f};
        if (node < n) v = *(const float4*)&hs[(size_t)node * 64 + c4];
        *(float4*)&acc[r * 64 + c4] = v;
    }
    int beg = bstart[b], end = bstart[b + 1];
    __syncthreads();

    for (int base = beg + wave * 64; base < end; base += 256) {
        int m = end - base;
        if (m > 64) m = 64;
        unsigned p = pairs[base + (f < m ? f : m - 1)];  // 64 edges coalesced into lanes
        int i = 0;
        for (; i + 4 <= m; i += 4) {
            unsigned p0 = __shfl(p, i);
            unsigned p1 = __shfl(p, i + 1);
            unsigned p2 = __shfl(p, i + 2);
            unsigned p3 = __shfl(p, i + 3);
            float v0 = hs[(size_t)(p0 & 0xffffu) * 64 + f];
            float v1 = hs[(size_t)(p1 & 0xffffu) * 64 + f];
            float v2 = hs[(size_t)(p2 & 0xffffu) * 64 + f];
            float v3 = hs[(size_t)(p3 & 0xffffu) * 64 + f];
            atomicAdd(&acc[(p0 >> 16) * 64 + f], v0);
            atomicAdd(&acc[(p1 >> 16) * 64 + f], v1);
            atomicAdd(&acc[(p2 >> 16) * 64 + f], v2);
            atomicAdd(&acc[(p3 >> 16) * 64 + f], v3);
        }
        for (; i < m; ++i) {
            unsigned pp = __shfl(p, i);
            atomicAdd(&acc[(pp >> 16) * 64 + f], hs[(size_t)(pp & 0xffffu) * 64 + f]);
        }
    }
    __syncthreads();

    // epilogue: scale by dinv[d], bias, relu, float4 store
    for (int idx4 = tid; idx4 < 64 * 16; idx4 += 256) {
        int r = idx4 >> 4, c4 = (idx4 & 15) * 4;
        int node = node0 + r;
        if (node < n) {
            float s = dinv[node];
            float4 v = *(float4*)&acc[r * 64 + c4];
            float4 o;
            o.x = fmaxf(v.x * s + bias[c4 + 0], 0.f);
            o.y = fmaxf(v.y * s + bias[c4 + 1], 0.f);
            o.z = fmaxf(v.z * s + bias[c4 + 2], 0.f);
            o.w = fmaxf(v.w * s + bias[c4 + 3], 0.f);
            *(float4*)&outp[(size_t)node * 64 + c4] = o;
        }
    }
}

// ---------------- fused segmented mean-pool + MLP head ----------------
__device__ __forceinline__ int lower_bound_dev(const int* __restrict__ a, int n, int v) {
    int lo = 0, hi = n;
    while (lo < hi) {
        int m = (lo + hi) >> 1;
        if (a[m] < v) lo = m + 1; else hi = m;
    }
    return lo;
}

__global__ void pool_head_kernel(const float* __restrict__ h, const int* __restrict__ batch,
                                 const float* __restrict__ W1, const float* __restrict__ b1,
                                 const float* __restrict__ W2, const float* __restrict__ b2,
                                 float* __restrict__ out, int nNodes, int nGraphs) {
    __shared__ float p[64];
    __shared__ float t[64];
    int g = blockIdx.x;
    int f = threadIdx.x;  // 64 threads
    int lo = lower_bound_dev(batch, nNodes, g);
    int hi = lower_bound_dev(batch, nNodes, g + 1);
    float sum = 0.0f;
    for (int i = lo; i < hi; ++i) sum += h[i * 64 + f];
    float inv = 1.0f / fmaxf((float)(hi - lo), 1.0f);
    p[f] = sum * inv;
    __syncthreads();
    float acc = b1[f];
#pragma unroll
    for (int k = 0; k < 64; ++k) acc += p[k] * W1[k * 64 + f];
    t[f] = fmaxf(acc, 0.0f);
    __syncthreads();
    if (f < OUT_DIM) {
        float acc2 = b2[f];
#pragma unroll
        for (int k = 0; k < 64; ++k) acc2 += t[k] * W2[k * OUT_DIM + f];
        out[g * OUT_DIM + f] = acc2;
    }
    if (g == 0 && f == 0) out[nGraphs * OUT_DIM] = 0.0f;  // trailing scalar output
}

extern "C" void kernel_launch(void* const* d_in, const int* in_sizes, int n_in,
                              void* d_out, int out_size, void* d_ws, size_t ws_size,
                              hipStream_t stream) {
    const float* x      = (const float*)d_in[0];
    const int*   eidx   = (const int*)d_in[1];
    const int*   batch  = (const int*)d_in[2];
    const float* W1     = (const float*)d_in[3];
    const float* b1     = (const float*)d_in[4];
    const float* W2     = (const float*)d_in[5];
    const float* b2     = (const float*)d_in[6];
    const float* W3     = (const float*)d_in[7];
    const float* b3     = (const float*)d_in[8];
    const float* lin_W1 = (const float*)d_in[9];
    const float* lin_b1 = (const float*)d_in[10];
    const float* lin_W2 = (const float*)d_in[11];
    const float* lin_b2 = (const float*)d_in[12];
    float* out = (float*)d_out;

    const int E = in_sizes[1] / 2;
    const int N = N_NODES;
    const int NF = N * HID;

    const int* src = eidx;
    const int* dst = eidx + E;

    // workspace layout
    float* ws = (float*)d_ws;
    float* buf1 = ws;                   // hs (pre-scaled linear out) [N, 64]
    float* buf2 = buf1 + NF;            // h                          [N, 64]
    float* dinv = buf2 + NF;            // [N]
    int* cnt      = (int*)(dinv + N);   // [N]
    int* bsum     = cnt + N;            // [NB_BUCK]
    int* bstart   = bsum + NB_BUCK;     // [NB_BUCK+1]
    int* bcursor  = bstart + NB_BUCK + 1;  // [NB_BUCK]
    unsigned* pairs = (unsigned*)(bcursor + NB_BUCK);  // [E]

    const int B = 256;
    const int TILES = (N + 63) / 64;  // 782

    // ---- bucketed edge structure + dinv ----
    zero_i_kernel<<<(N + B - 1) / B, B, 0, stream>>>(cnt, N);
    hist_kernel<<<(E + B - 1) / B, B, 0, stream>>>(dst, cnt, E);
    bsum_dinv_kernel<<<NB_BUCK, 64, 0, stream>>>(cnt, dinv, bsum, N);
    bscan_kernel<<<1, 1024, 0, stream>>>(bsum, bstart, bcursor, NB_BUCK, E);
    bfill_kernel<<<(E + B - 1) / B, B, 0, stream>>>(src, dst, bcursor, pairs, E);

    // ---- layer 1 ----
    linear_kernel<IN_DIM><<<TILES, 256, 0, stream>>>(x, W1, dinv, buf1, N);
    gather_bucket_kernel<<<NB_BUCK, 256, 0, stream>>>(buf1, pairs, bstart, dinv, b1, buf2, N);

    // ---- layer 2 ----
    linear_kernel<HID><<<TILES, 256, 0, stream>>>(buf2, W2, dinv, buf1, N);
    gather_bucket_kernel<<<NB_BUCK, 256, 0, stream>>>(buf1, pairs, bstart, dinv, b2, buf2, N);

    // ---- layer 3 ----
    linear_kernel<HID><<<TILES, 256, 0, stream>>>(buf2, W3, dinv, buf1, N);
    gather_bucket_kernel<<<NB_BUCK, 256, 0, stream>>>(buf1, pairs, bstart, dinv, b3, buf2, N);

    // ---- fused pool + head ----
    pool_head_kernel<<<N_GRAPHS, 64, 0, stream>>>(buf2, batch, lin_W1, lin_b1, lin_W2, lin_b2,
                                                  out, N, N_GRAPHS);
}

// Round 6
// 517.564 us; speedup vs baseline: 2.8745x; 2.8745x over previous
//
#include <hip/hip_runtime.h>
#include <hip/hip_bf16.h>

#define N_NODES 50000
#define N_EDGES 800000
#define N_GRAPHS 500
#define IN_DIM 128
#define HID 64
#define OUT_DIM 10
#define NB_BUCK ((N_NODES + 63) >> 6)  // 782 buckets of 64 nodes

// ---------------- zero ----------------
__global__ void zero_i_kernel(int* __restrict__ p, int n) {
    int i = blockIdx.x * blockDim.x + threadIdx.x;
    if (i < n) p[i] = 0;
}

// ---------------- degree histogram ----------------
__global__ void hist_kernel(const int* __restrict__ dst, int* __restrict__ cnt, int e) {
    int i = blockIdx.x * blockDim.x + threadIdx.x;
    if (i < e) atomicAdd(&cnt[dst[i]], 1);
}

// ---------------- per-bucket degree sum + dinv ----------------
__global__ void bsum_dinv_kernel(const int* __restrict__ cnt, float* __restrict__ dinv,
                                 int* __restrict__ bsum, int n) {
    int b = blockIdx.x;
    int lane = threadIdx.x;  // 64
    int i = b * 64 + lane;
    int c = (i < n) ? cnt[i] : 0;
    if (i < n) dinv[i] = rsqrtf((float)(c + 1));
    int v = c;
    for (int off = 32; off; off >>= 1) v += __shfl_down(v, off);
    if (lane == 0) bsum[b] = v;
}

// ---------------- exclusive scan over bucket sums (single block) ----------------
__global__ void bscan_kernel(const int* __restrict__ bsum, int* __restrict__ bstart,
                             int* __restrict__ bcursor, int nb, int e) {
    __shared__ int s[1024];
    int t = threadIdx.x;
    int v = (t < nb) ? bsum[t] : 0;
    s[t] = v;
    __syncthreads();
    for (int off = 1; off < 1024; off <<= 1) {
        int x = (t >= off) ? s[t - off] : 0;
        __syncthreads();
        s[t] += x;
        __syncthreads();
    }
    int excl = s[t] - v;
    if (t < nb) {
        bstart[t] = excl;
        bcursor[t] = excl;
    }
    if (t == 0) bstart[nb] = e;
}

// ---------------- per-node row starts: rs[node] = bstart[b] + prefix within bucket ----------------
__global__ void node_rs_kernel(const int* __restrict__ cnt, const int* __restrict__ bstart,
                               int* __restrict__ rs, int n, int e) {
    int b = blockIdx.x;
    int lane = threadIdx.x;  // 64
    int node = b * 64 + lane;
    int c = (node < n) ? cnt[node] : 0;
    int v = c;
    for (int off = 1; off < 64; off <<= 1) {
        int t = __shfl_up(v, off);
        if (lane >= off) v += t;
    }
    int excl = v - c;
    if (node < n) rs[node] = bstart[b] + excl;
    if (b == 0 && lane == 0) rs[n] = e;
}

// ---------------- bucket fill: packed (dlocal<<16 | src), adjacent slots per bucket ----------------
__global__ void bfill_kernel(const int* __restrict__ src, const int* __restrict__ dst,
                             int* __restrict__ bcursor, unsigned* __restrict__ pairs, int e) {
    int i = blockIdx.x * blockDim.x + threadIdx.x;
    if (i < e) {
        int d = dst[i];
        int slot = atomicAdd(&bcursor[d >> 6], 1);
        pairs[slot] = ((unsigned)(d & 63) << 16) | (unsigned)src[i];
    }
}

// ---------------- pairs -> node-granular csr_src (writes stay in bucket's 4KB range) ----------------
__global__ __launch_bounds__(256) void csr_scatter_kernel(
    const unsigned* __restrict__ pairs, const int* __restrict__ bstart,
    const int* __restrict__ rs, int* __restrict__ csr_src, int n) {
    __shared__ int cur[64];
    int b = blockIdx.x;
    int tid = threadIdx.x;
    if (tid < 64) {
        int node = b * 64 + tid;
        cur[tid] = (node < n) ? rs[node] : 0;
    }
    __syncthreads();
    int beg = bstart[b], end = bstart[b + 1];
    for (int i = beg + tid; i < end; i += 256) {
        unsigned p = pairs[i];
        int slot = atomicAdd(&cur[p >> 16], 1);
        csr_src[slot] = (int)(p & 0xffffu);
    }
}

// ---------------- tiled linear (+ dinv pre-scale) ----------------
// C[node,f] = dinv[node] * sum_k A[node,k] * W[k,f]
// 256 threads, 64-node x 64-feat tile, 4x4 micro-tile per thread; A+W staged in LDS.
template <int K>
__global__ __launch_bounds__(256) void linear_kernel(
    const float* __restrict__ A, const float* __restrict__ W,
    const float* __restrict__ dinv, float* __restrict__ C, int n) {
    __shared__ float As[64][K + 4];  // +4 pad: float4-aligned, breaks pow2 bank stride
    __shared__ float Ws[K][64];
    int tid = threadIdx.x;
    int tx = tid & 15;   // feat group
    int ty = tid >> 4;   // node group
    int block0 = blockIdx.x * 64;
    int rows = n - block0;
    if (rows > 64) rows = 64;

    const float* Abase = A + (size_t)block0 * K;
    int totalA4 = (rows * K) >> 2;
    for (int i4 = tid; i4 < totalA4; i4 += 256) {
        int i = i4 << 2;
        float4 v = *(const float4*)(Abase + i);
        *(float4*)&As[i / K][i % K] = v;  // K pow2 -> shifts
    }
    {
        const float4* Wv = (const float4*)W;
        float4* Wsv = (float4*)&Ws[0][0];
        for (int i = tid; i < K * 16; i += 256) Wsv[i] = Wv[i];
    }
    __syncthreads();

    float acc[4][4] = {};
#pragma unroll 2
    for (int k = 0; k < K; k += 4) {
        float4 a[4];
#pragma unroll
        for (int i = 0; i < 4; ++i) a[i] = *(const float4*)&As[ty * 4 + i][k];
        float4 w[4];
#pragma unroll
        for (int kk = 0; kk < 4; ++kk) w[kk] = *(const float4*)&Ws[k + kk][tx * 4];
#pragma unroll
        for (int i = 0; i < 4; ++i) {
            float av[4] = {a[i].x, a[i].y, a[i].z, a[i].w};
#pragma unroll
            for (int kk = 0; kk < 4; ++kk) {
                acc[i][0] += av[kk] * w[kk].x;
                acc[i][1] += av[kk] * w[kk].y;
                acc[i][2] += av[kk] * w[kk].z;
                acc[i][3] += av[kk] * w[kk].w;
            }
        }
    }

#pragma unroll
    for (int i = 0; i < 4; ++i) {
        int r = ty * 4 + i;
        if (r < rows) {
            float s = dinv[block0 + r];
            float4 v = {acc[i][0] * s, acc[i][1] * s, acc[i][2] * s, acc[i][3] * s};
            *(float4*)&C[(size_t)(block0 + r) * 64 + tx * 4] = v;
        }
    }
}

// ---------------- per-node float4 gather; fused self-loop+bias+relu ----------------
// lane = (edge-group eg 0..3) x (feat-quad 0..15); wave per node.
// out[d,f] = relu( dinv[d] * ( hs[d,f] + sum_{s in N(d)} hs[s,f] ) + b[f] )
__global__ __launch_bounds__(256) void gather_kernel(
    const float* __restrict__ hs, const int* __restrict__ rs,
    const int* __restrict__ csr_src, const float* __restrict__ dinv,
    const float* __restrict__ bias, float* __restrict__ outp, int n) {
    int wave = threadIdx.x >> 6;
    int node = blockIdx.x * 4 + wave;
    if (node >= n) return;
    int lane = threadIdx.x & 63;
    int eg = lane >> 4;         // edge group
    int f4 = (lane & 15) << 2;  // feature quad
    int beg = rs[node], end = rs[node + 1];
    float4 acc = {0.f, 0.f, 0.f, 0.f};
    if (eg == 0) acc = *(const float4*)&hs[(size_t)node * 64 + f4];  // self-loop (pre-scaled)
    int j = beg + eg;
    for (; j + 4 < end; j += 8) {  // 2 edges per lane-group in flight
        int s0 = csr_src[j];
        int s1 = csr_src[j + 4];
        float4 v0 = *(const float4*)&hs[(size_t)s0 * 64 + f4];
        float4 v1 = *(const float4*)&hs[(size_t)s1 * 64 + f4];
        acc.x += v0.x + v1.x;
        acc.y += v0.y + v1.y;
        acc.z += v0.z + v1.z;
        acc.w += v0.w + v1.w;
    }
    if (j < end) {
        int s = csr_src[j];
        float4 v = *(const float4*)&hs[(size_t)s * 64 + f4];
        acc.x += v.x; acc.y += v.y; acc.z += v.z; acc.w += v.w;
    }
    // merge the 4 edge groups: butterfly over lane bits 4,5
    acc.x += __shfl_xor(acc.x, 16); acc.y += __shfl_xor(acc.y, 16);
    acc.z += __shfl_xor(acc.z, 16); acc.w += __shfl_xor(acc.w, 16);
    acc.x += __shfl_xor(acc.x, 32); acc.y += __shfl_xor(acc.y, 32);
    acc.z += __shfl_xor(acc.z, 32); acc.w += __shfl_xor(acc.w, 32);
    if (eg == 0) {
        float s = dinv[node];
        float4 bb = *(const float4*)&bias[f4];
        float4 o;
        o.x = fmaxf(acc.x * s + bb.x, 0.f);
        o.y = fmaxf(acc.y * s + bb.y, 0.f);
        o.z = fmaxf(acc.z * s + bb.z, 0.f);
        o.w = fmaxf(acc.w * s + bb.w, 0.f);
        *(float4*)&outp[(size_t)node * 64 + f4] = o;
    }
}

// ---------------- fused segmented mean-pool + MLP head ----------------
__device__ __forceinline__ int lower_bound_dev(const int* __restrict__ a, int n, int v) {
    int lo = 0, hi = n;
    while (lo < hi) {
        int m = (lo + hi) >> 1;
        if (a[m] < v) lo = m + 1; else hi = m;
    }
    return lo;
}

__global__ void pool_head_kernel(const float* __restrict__ h, const int* __restrict__ batch,
                                 const float* __restrict__ W1, const float* __restrict__ b1,
                                 const float* __restrict__ W2, const float* __restrict__ b2,
                                 float* __restrict__ out, int nNodes, int nGraphs) {
    __shared__ float p[64];
    __shared__ float t[64];
    int g = blockIdx.x;
    int f = threadIdx.x;  // 64 threads
    int lo = lower_bound_dev(batch, nNodes, g);
    int hi = lower_bound_dev(batch, nNodes, g + 1);
    float sum = 0.0f;
    for (int i = lo; i < hi; ++i) sum += h[i * 64 + f];
    float inv = 1.0f / fmaxf((float)(hi - lo), 1.0f);
    p[f] = sum * inv;
    __syncthreads();
    float acc = b1[f];
#pragma unroll
    for (int k = 0; k < 64; ++k) acc += p[k] * W1[k * 64 + f];
    t[f] = fmaxf(acc, 0.0f);
    __syncthreads();
    if (f < OUT_DIM) {
        float acc2 = b2[f];
#pragma unroll
        for (int k = 0; k < 64; ++k) acc2 += t[k] * W2[k * OUT_DIM + f];
        out[g * OUT_DIM + f] = acc2;
    }
    if (g == 0 && f == 0) out[nGraphs * OUT_DIM] = 0.0f;  // trailing scalar output
}

extern "C" void kernel_launch(void* const* d_in, const int* in_sizes, int n_in,
                              void* d_out, int out_size, void* d_ws, size_t ws_size,
                              hipStream_t stream) {
    const float* x      = (const float*)d_in[0];
    const int*   eidx   = (const int*)d_in[1];
    const int*   batch  = (const int*)d_in[2];
    const float* W1     = (const float*)d_in[3];
    const float* b1     = (const float*)d_in[4];
    const float* W2     = (const float*)d_in[5];
    const float* b2     = (const float*)d_in[6];
    const float* W3     = (const float*)d_in[7];
    const float* b3     = (const float*)d_in[8];
    const float* lin_W1 = (const float*)d_in[9];
    const float* lin_b1 = (const float*)d_in[10];
    const float* lin_W2 = (const float*)d_in[11];
    const float* lin_b2 = (const float*)d_in[12];
    float* out = (float*)d_out;

    const int E = in_sizes[1] / 2;
    const int N = N_NODES;
    const int NF = N * HID;

    const int* src = eidx;
    const int* dst = eidx + E;

    // workspace layout
    float* ws = (float*)d_ws;
    float* buf1 = ws;                   // hs (pre-scaled linear out) [N, 64]
    float* buf2 = buf1 + NF;            // h                          [N, 64]
    float* dinv = buf2 + NF;            // [N]
    int* cnt      = (int*)(dinv + N);   // [N]
    int* bsum     = cnt + N;            // [NB_BUCK]
    int* bstart   = bsum + NB_BUCK;     // [NB_BUCK+1]
    int* bcursor  = bstart + NB_BUCK + 1;  // [NB_BUCK]
    int* rs       = bcursor + NB_BUCK;  // [N+1]
    int* csr_src  = rs + N + 1;         // [E]
    unsigned* pairs = (unsigned*)(csr_src + E);  // [E]

    const int B = 256;
    const int TILES = (N + 63) / 64;  // 782

    // ---- edge structure + dinv ----
    zero_i_kernel<<<(N + B - 1) / B, B, 0, stream>>>(cnt, N);
    hist_kernel<<<(E + B - 1) / B, B, 0, stream>>>(dst, cnt, E);
    bsum_dinv_kernel<<<NB_BUCK, 64, 0, stream>>>(cnt, dinv, bsum, N);
    bscan_kernel<<<1, 1024, 0, stream>>>(bsum, bstart, bcursor, NB_BUCK, E);
    node_rs_kernel<<<NB_BUCK, 64, 0, stream>>>(cnt, bstart, rs, N, E);
    bfill_kernel<<<(E + B - 1) / B, B, 0, stream>>>(src, dst, bcursor, pairs, E);
    csr_scatter_kernel<<<NB_BUCK, 256, 0, stream>>>(pairs, bstart, rs, csr_src, N);

    // ---- layer 1 ----
    linear_kernel<IN_DIM><<<TILES, 256, 0, stream>>>(x, W1, dinv, buf1, N);
    gather_kernel<<<(N + 3) / 4, 256, 0, stream>>>(buf1, rs, csr_src, dinv, b1, buf2, N);

    // ---- layer 2 ----
    linear_kernel<HID><<<TILES, 256, 0, stream>>>(buf2, W2, dinv, buf1, N);
    gather_kernel<<<(N + 3) / 4, 256, 0, stream>>>(buf1, rs, csr_src, dinv, b2, buf2, N);

    // ---- layer 3 ----
    linear_kernel<HID><<<TILES, 256, 0, stream>>>(buf2, W3, dinv, buf1, N);
    gather_kernel<<<(N + 3) / 4, 256, 0, stream>>>(buf1, rs, csr_src, dinv, b3, buf2, N);

    // ---- fused pool + head ----
    pool_head_kernel<<<N_GRAPHS, 64, 0, stream>>>(buf2, batch, lin_W1, lin_b1, lin_W2, lin_b2,
                                                  out, N, N_GRAPHS);
}

// Round 7
// 374.774 us; speedup vs baseline: 3.9697x; 1.3810x over previous
//
#include <hip/hip_runtime.h>
#include <hip/hip_bf16.h>

#define N_NODES 50000
#define N_EDGES 800000
#define N_GRAPHS 500
#define IN_DIM 128
#define HID 64
#define OUT_DIM 10
#define NB_BUCK ((N_NODES + 63) >> 6)  // 782 buckets of 64 nodes
#define CUR_STRIDE 16                  // one cursor per 64B cache line (atomic queues are per-line!)

// ---------------- zero ----------------
__global__ void zero_i_kernel(int* __restrict__ p, int n) {
    int i = blockIdx.x * blockDim.x + threadIdx.x;
    if (i < n) p[i] = 0;
}

// ---------------- degree histogram ----------------
__global__ void hist_kernel(const int* __restrict__ dst, int* __restrict__ cnt, int e) {
    int i = blockIdx.x * blockDim.x + threadIdx.x;
    if (i < e) atomicAdd(&cnt[dst[i]], 1);
}

// ---------------- per-bucket degree sum + dinv ----------------
__global__ void bsum_dinv_kernel(const int* __restrict__ cnt, float* __restrict__ dinv,
                                 int* __restrict__ bsum, int n) {
    int b = blockIdx.x;
    int lane = threadIdx.x;  // 64
    int i = b * 64 + lane;
    int c = (i < n) ? cnt[i] : 0;
    if (i < n) dinv[i] = rsqrtf((float)(c + 1));
    int v = c;
    for (int off = 32; off; off >>= 1) v += __shfl_down(v, off);
    if (lane == 0) bsum[b] = v;
}

// ---------------- exclusive scan over bucket sums (single block) ----------------
__global__ void bscan_kernel(const int* __restrict__ bsum, int* __restrict__ bstart,
                             int* __restrict__ bcursor, int nb, int e) {
    __shared__ int s[1024];
    int t = threadIdx.x;
    int v = (t < nb) ? bsum[t] : 0;
    s[t] = v;
    __syncthreads();
    for (int off = 1; off < 1024; off <<= 1) {
        int x = (t >= off) ? s[t - off] : 0;
        __syncthreads();
        s[t] += x;
        __syncthreads();
    }
    int excl = s[t] - v;
    if (t < nb) {
        bstart[t] = excl;
        bcursor[t * CUR_STRIDE] = excl;  // line-padded cursor
    }
    if (t == 0) bstart[nb] = e;
}

// ---------------- per-node row starts: rs[node] = bstart[b] + prefix within bucket ----------------
__global__ void node_rs_kernel(const int* __restrict__ cnt, const int* __restrict__ bstart,
                               int* __restrict__ rs, int n, int e) {
    int b = blockIdx.x;
    int lane = threadIdx.x;  // 64
    int node = b * 64 + lane;
    int c = (node < n) ? cnt[node] : 0;
    int v = c;
    for (int off = 1; off < 64; off <<= 1) {
        int t = __shfl_up(v, off);
        if (lane >= off) v += t;
    }
    int excl = v - c;
    if (node < n) rs[node] = bstart[b] + excl;
    if (b == 0 && lane == 0) rs[n] = e;
}

// ---------------- bucket fill: packed (dlocal<<16 | src), adjacent slots per bucket ----------------
__global__ void bfill_kernel(const int* __restrict__ src, const int* __restrict__ dst,
                             int* __restrict__ bcursor, unsigned* __restrict__ pairs, int e) {
    int i = blockIdx.x * blockDim.x + threadIdx.x;
    if (i < e) {
        int d = dst[i];
        int slot = atomicAdd(&bcursor[(d >> 6) * CUR_STRIDE], 1);  // line-padded: no cross-counter serialization
        pairs[slot] = ((unsigned)(d & 63) << 16) | (unsigned)src[i];
    }
}

// ---------------- pairs -> node-granular csr_src (writes stay in bucket's 4KB range) ----------------
__global__ __launch_bounds__(256) void csr_scatter_kernel(
    const unsigned* __restrict__ pairs, const int* __restrict__ bstart,
    const int* __restrict__ rs, int* __restrict__ csr_src, int n) {
    __shared__ int cur[64];
    int b = blockIdx.x;
    int tid = threadIdx.x;
    if (tid < 64) {
        int node = b * 64 + tid;
        cur[tid] = (node < n) ? rs[node] : 0;
    }
    __syncthreads();
    int beg = bstart[b], end = bstart[b + 1];
    for (int i = beg + tid; i < end; i += 256) {
        unsigned p = pairs[i];
        int slot = atomicAdd(&cur[p >> 16], 1);
        csr_src[slot] = (int)(p & 0xffffu);
    }
}

// ---------------- tiled linear (+ dinv pre-scale) ----------------
// C[node,f] = dinv[node] * sum_k A[node,k] * W[k,f]
// 256 threads, 64-node x 64-feat tile, 4x4 micro-tile per thread; A+W staged in LDS.
template <int K>
__global__ __launch_bounds__(256) void linear_kernel(
    const float* __restrict__ A, const float* __restrict__ W,
    const float* __restrict__ dinv, float* __restrict__ C, int n) {
    __shared__ float As[64][K + 4];  // +4 pad: float4-aligned, breaks pow2 bank stride
    __shared__ float Ws[K][64];
    int tid = threadIdx.x;
    int tx = tid & 15;   // feat group
    int ty = tid >> 4;   // node group
    int block0 = blockIdx.x * 64;
    int rows = n - block0;
    if (rows > 64) rows = 64;

    const float* Abase = A + (size_t)block0 * K;
    int totalA4 = (rows * K) >> 2;
    for (int i4 = tid; i4 < totalA4; i4 += 256) {
        int i = i4 << 2;
        float4 v = *(const float4*)(Abase + i);
        *(float4*)&As[i / K][i % K] = v;  // K pow2 -> shifts
    }
    {
        const float4* Wv = (const float4*)W;
        float4* Wsv = (float4*)&Ws[0][0];
        for (int i = tid; i < K * 16; i += 256) Wsv[i] = Wv[i];
    }
    __syncthreads();

    float acc[4][4] = {};
#pragma unroll 2
    for (int k = 0; k < K; k += 4) {
        float4 a[4];
#pragma unroll
        for (int i = 0; i < 4; ++i) a[i] = *(const float4*)&As[ty * 4 + i][k];
        float4 w[4];
#pragma unroll
        for (int kk = 0; kk < 4; ++kk) w[kk] = *(const float4*)&Ws[k + kk][tx * 4];
#pragma unroll
        for (int i = 0; i < 4; ++i) {
            float av[4] = {a[i].x, a[i].y, a[i].z, a[i].w};
#pragma unroll
            for (int kk = 0; kk < 4; ++kk) {
                acc[i][0] += av[kk] * w[kk].x;
                acc[i][1] += av[kk] * w[kk].y;
                acc[i][2] += av[kk] * w[kk].z;
                acc[i][3] += av[kk] * w[kk].w;
            }
        }
    }

#pragma unroll
    for (int i = 0; i < 4; ++i) {
        int r = ty * 4 + i;
        if (r < rows) {
            float s = dinv[block0 + r];
            float4 v = {acc[i][0] * s, acc[i][1] * s, acc[i][2] * s, acc[i][3] * s};
            *(float4*)&C[(size_t)(block0 + r) * 64 + tx * 4] = v;
        }
    }
}

// ---------------- per-node float4 gather; fused self-loop+bias+relu ----------------
// lane = (edge-group eg 0..3) x (feat-quad 0..15); wave per node.
// out[d,f] = relu( dinv[d] * ( hs[d,f] + sum_{s in N(d)} hs[s,f] ) + b[f] )
__global__ __launch_bounds__(256) void gather_kernel(
    const float* __restrict__ hs, const int* __restrict__ rs,
    const int* __restrict__ csr_src, const float* __restrict__ dinv,
    const float* __restrict__ bias, float* __restrict__ outp, int n) {
    int wave = threadIdx.x >> 6;
    int node = blockIdx.x * 4 + wave;
    if (node >= n) return;
    int lane = threadIdx.x & 63;
    int eg = lane >> 4;         // edge group
    int f4 = (lane & 15) << 2;  // feature quad
    int beg = rs[node], end = rs[node + 1];
    float4 acc = {0.f, 0.f, 0.f, 0.f};
    if (eg == 0) acc = *(const float4*)&hs[(size_t)node * 64 + f4];  // self-loop (pre-scaled)
    int j = beg + eg;
    for (; j + 4 < end; j += 8) {  // 2 edges per lane-group in flight
        int s0 = csr_src[j];
        int s1 = csr_src[j + 4];
        float4 v0 = *(const float4*)&hs[(size_t)s0 * 64 + f4];
        float4 v1 = *(const float4*)&hs[(size_t)s1 * 64 + f4];
        acc.x += v0.x + v1.x;
        acc.y += v0.y + v1.y;
        acc.z += v0.z + v1.z;
        acc.w += v0.w + v1.w;
    }
    if (j < end) {
        int s = csr_src[j];
        float4 v = *(const float4*)&hs[(size_t)s * 64 + f4];
        acc.x += v.x; acc.y += v.y; acc.z += v.z; acc.w += v.w;
    }
    // merge the 4 edge groups: butterfly over lane bits 4,5
    acc.x += __shfl_xor(acc.x, 16); acc.y += __shfl_xor(acc.y, 16);
    acc.z += __shfl_xor(acc.z, 16); acc.w += __shfl_xor(acc.w, 16);
    acc.x += __shfl_xor(acc.x, 32); acc.y += __shfl_xor(acc.y, 32);
    acc.z += __shfl_xor(acc.z, 32); acc.w += __shfl_xor(acc.w, 32);
    if (eg == 0) {
        float s = dinv[node];
        float4 bb = *(const float4*)&bias[f4];
        float4 o;
        o.x = fmaxf(acc.x * s + bb.x, 0.f);
        o.y = fmaxf(acc.y * s + bb.y, 0.f);
        o.z = fmaxf(acc.z * s + bb.z, 0.f);
        o.w = fmaxf(acc.w * s + bb.w, 0.f);
        *(float4*)&outp[(size_t)node * 64 + f4] = o;
    }
}

// ---------------- fused segmented mean-pool + MLP head ----------------
__device__ __forceinline__ int lower_bound_dev(const int* __restrict__ a, int n, int v) {
    int lo = 0, hi = n;
    while (lo < hi) {
        int m = (lo + hi) >> 1;
        if (a[m] < v) lo = m + 1; else hi = m;
    }
    return lo;
}

__global__ void pool_head_kernel(const float* __restrict__ h, const int* __restrict__ batch,
                                 const float* __restrict__ W1, const float* __restrict__ b1,
                                 const float* __restrict__ W2, const float* __restrict__ b2,
                                 float* __restrict__ out, int nNodes, int nGraphs) {
    __shared__ float p[64];
    __shared__ float t[64];
    int g = blockIdx.x;
    int f = threadIdx.x;  // 64 threads
    int lo = lower_bound_dev(batch, nNodes, g);
    int hi = lower_bound_dev(batch, nNodes, g + 1);
    float sum = 0.0f;
    for (int i = lo; i < hi; ++i) sum += h[i * 64 + f];
    float inv = 1.0f / fmaxf((float)(hi - lo), 1.0f);
    p[f] = sum * inv;
    __syncthreads();
    float acc = b1[f];
#pragma unroll
    for (int k = 0; k < 64; ++k) acc += p[k] * W1[k * 64 + f];
    t[f] = fmaxf(acc, 0.0f);
    __syncthreads();
    if (f < OUT_DIM) {
        float acc2 = b2[f];
#pragma unroll
        for (int k = 0; k < 64; ++k) acc2 += t[k] * W2[k * OUT_DIM + f];
        out[g * OUT_DIM + f] = acc2;
    }
    if (g == 0 && f == 0) out[nGraphs * OUT_DIM] = 0.0f;  // trailing scalar output
}

extern "C" void kernel_launch(void* const* d_in, const int* in_sizes, int n_in,
                              void* d_out, int out_size, void* d_ws, size_t ws_size,
                              hipStream_t stream) {
    const float* x      = (const float*)d_in[0];
    const int*   eidx   = (const int*)d_in[1];
    const int*   batch  = (const int*)d_in[2];
    const float* W1     = (const float*)d_in[3];
    const float* b1     = (const float*)d_in[4];
    const float* W2     = (const float*)d_in[5];
    const float* b2     = (const float*)d_in[6];
    const float* W3     = (const float*)d_in[7];
    const float* b3     = (const float*)d_in[8];
    const float* lin_W1 = (const float*)d_in[9];
    const float* lin_b1 = (const float*)d_in[10];
    const float* lin_W2 = (const float*)d_in[11];
    const float* lin_b2 = (const float*)d_in[12];
    float* out = (float*)d_out;

    const int E = in_sizes[1] / 2;
    const int N = N_NODES;
    const int NF = N * HID;

    const int* src = eidx;
    const int* dst = eidx + E;

    // workspace layout
    float* ws = (float*)d_ws;
    float* buf1 = ws;                   // hs (pre-scaled linear out) [N, 64]
    float* buf2 = buf1 + NF;            // h                          [N, 64]
    float* dinv = buf2 + NF;            // [N]
    int* cnt      = (int*)(dinv + N);   // [N]
    int* bsum     = cnt + N;            // [NB_BUCK]
    int* bstart   = bsum + NB_BUCK;     // [NB_BUCK+1]
    int* bcursor  = bstart + NB_BUCK + 1;        // [NB_BUCK*CUR_STRIDE] line-padded
    int* rs       = bcursor + NB_BUCK * CUR_STRIDE;  // [N+1]
    int* csr_src  = rs + N + 1;         // [E]
    unsigned* pairs = (unsigned*)(csr_src + E);  // [E]

    const int B = 256;
    const int TILES = (N + 63) / 64;  // 782

    // ---- edge structure + dinv ----
    zero_i_kernel<<<(N + B - 1) / B, B, 0, stream>>>(cnt, N);
    hist_kernel<<<(E + B - 1) / B, B, 0, stream>>>(dst, cnt, E);
    bsum_dinv_kernel<<<NB_BUCK, 64, 0, stream>>>(cnt, dinv, bsum, N);
    bscan_kernel<<<1, 1024, 0, stream>>>(bsum, bstart, bcursor, NB_BUCK, E);
    node_rs_kernel<<<NB_BUCK, 64, 0, stream>>>(cnt, bstart, rs, N, E);
    bfill_kernel<<<(E + B - 1) / B, B, 0, stream>>>(src, dst, bcursor, pairs, E);
    csr_scatter_kernel<<<NB_BUCK, 256, 0, stream>>>(pairs, bstart, rs, csr_src, N);

    // ---- layer 1 ----
    linear_kernel<IN_DIM><<<TILES, 256, 0, stream>>>(x, W1, dinv, buf1, N);
    gather_kernel<<<(N + 3) / 4, 256, 0, stream>>>(buf1, rs, csr_src, dinv, b1, buf2, N);

    // ---- layer 2 ----
    linear_kernel<HID><<<TILES, 256, 0, stream>>>(buf2, W2, dinv, buf1, N);
    gather_kernel<<<(N + 3) / 4, 256, 0, stream>>>(buf1, rs, csr_src, dinv, b2, buf2, N);

    // ---- layer 3 ----
    linear_kernel<HID><<<TILES, 256, 0, stream>>>(buf2, W3, dinv, buf1, N);
    gather_kernel<<<(N + 3) / 4, 256, 0, stream>>>(buf1, rs, csr_src, dinv, b3, buf2, N);

    // ---- fused pool + head ----
    pool_head_kernel<<<N_GRAPHS, 64, 0, stream>>>(buf2, batch, lin_W1, lin_b1, lin_W2, lin_b2,
                                                  out, N, N_GRAPHS);
}

// Round 8
// 309.224 us; speedup vs baseline: 4.8112x; 1.2120x over previous
//
#include <hip/hip_runtime.h>
#include <hip/hip_bf16.h>

#define N_NODES 50000
#define N_EDGES 800000
#define N_GRAPHS 500
#define IN_DIM 128
#define HID 64
#define OUT_DIM 10
#define NB_BUCK ((N_NODES + 63) >> 6)  // 782 buckets of 64 nodes
#define NBLK 64                        // edge chunks: ~12.5k edges -> ~16 edges/bucket = 64B segments

// ---------------- P1: per-chunk bucket histogram (LDS, no global atomics) ----------------
__global__ __launch_bounds__(1024) void p1_hist_kernel(const int* __restrict__ dst,
                                                       int* __restrict__ bhist, int e, int epb) {
    __shared__ int h[NB_BUCK];
    int tid = threadIdx.x;
    int blk = blockIdx.x;
    for (int i = tid; i < NB_BUCK; i += 1024) h[i] = 0;
    __syncthreads();
    int e0 = blk * epb;
    int e1 = e0 + epb;
    if (e1 > e) e1 = e;
    for (int i = e0 + tid; i < e1; i += 1024) atomicAdd(&h[dst[i] >> 6], 1);
    __syncthreads();
    for (int i = tid; i < NB_BUCK; i += 1024) bhist[blk * NB_BUCK + i] = h[i];
}

// ---------------- scanA: per bucket, scan the 64 chunk counts -> chunk bases + bucket total ----
__global__ void scanA_kernel(const int* __restrict__ bhist, int* __restrict__ base,
                             int* __restrict__ bsum) {
    int b = blockIdx.x;     // bucket
    int lane = threadIdx.x; // 64 = NBLK
    int c = bhist[lane * NB_BUCK + b];
    int v = c;
#pragma unroll
    for (int off = 1; off < 64; off <<= 1) {
        int t = __shfl_up(v, off);
        if (lane >= off) v += t;
    }
    base[lane * NB_BUCK + b] = v - c;  // exclusive prefix for chunk `lane`
    if (lane == 63) bsum[b] = v;       // bucket total
}

// ---------------- bscan: exclusive scan over bucket totals ----------------
__global__ __launch_bounds__(1024) void bscan_kernel(const int* __restrict__ bsum,
                                                     int* __restrict__ bstart, int nb, int e) {
    __shared__ int s[1024];
    int t = threadIdx.x;
    int v = (t < nb) ? bsum[t] : 0;
    s[t] = v;
    __syncthreads();
    for (int off = 1; off < 1024; off <<= 1) {
        int x = (t >= off) ? s[t - off] : 0;
        __syncthreads();
        s[t] += x;
        __syncthreads();
    }
    if (t < nb) bstart[t] = s[t] - v;
    if (t == 0) bstart[nb] = e;
}

// ---------------- P2: place edges into bucket-grouped pairs (block-local dense segments) ------
__global__ __launch_bounds__(1024) void p2_place_kernel(
    const int* __restrict__ src, const int* __restrict__ dst, const int* __restrict__ bstart,
    const int* __restrict__ base, unsigned* __restrict__ pairs, int e, int epb) {
    __shared__ int h[NB_BUCK];   // local rank counters
    __shared__ int sb[NB_BUCK];  // global segment base for this chunk
    int tid = threadIdx.x;
    int blk = blockIdx.x;
    for (int i = tid; i < NB_BUCK; i += 1024) {
        h[i] = 0;
        sb[i] = bstart[i] + base[blk * NB_BUCK + i];
    }
    __syncthreads();
    int e0 = blk * epb;
    int e1 = e0 + epb;
    if (e1 > e) e1 = e;
    for (int i = e0 + tid; i < e1; i += 1024) {
        int d = dst[i];
        int b = d >> 6;
        int r = atomicAdd(&h[b], 1);
        pairs[sb[b] + r] = ((unsigned)(d & 63) << 16) | (unsigned)src[i];
    }
}

// ---------------- csr_scatter2: per bucket -> rs, dinv, csr_src (no global atomics) ----------
__global__ __launch_bounds__(256) void csr_scatter2_kernel(
    const unsigned* __restrict__ pairs, const int* __restrict__ bstart,
    int* __restrict__ rs, float* __restrict__ dinv, int* __restrict__ csr_src, int n) {
    __shared__ int lcnt[64];
    __shared__ int lcur[64];
    int b = blockIdx.x;
    int tid = threadIdx.x;
    int beg = bstart[b], end = bstart[b + 1];
    if (tid < 64) lcnt[tid] = 0;
    __syncthreads();
    for (int i = beg + tid; i < end; i += 256) atomicAdd(&lcnt[pairs[i] >> 16], 1);
    __syncthreads();
    if (tid < 64) {  // wave 0: scan the 64 node counts
        int c = lcnt[tid];
        int v = c;
#pragma unroll
        for (int off = 1; off < 64; off <<= 1) {
            int t = __shfl_up(v, off);
            if (tid >= off) v += t;
        }
        int excl = v - c;
        int node = b * 64 + tid;
        if (node <= n) {
            rs[node] = beg + excl;  // node==n lands on rs[N]=E (last bucket's tail)
            if (node < n) dinv[node] = rsqrtf((float)(c + 1));
        }
        lcur[tid] = beg + excl;
    }
    __syncthreads();
    for (int i = beg + tid; i < end; i += 256) {
        unsigned p = pairs[i];
        int slot = atomicAdd(&lcur[p >> 16], 1);
        csr_src[slot] = (int)(p & 0xffffu);
    }
}

// ---------------- tiled linear (+ dinv pre-scale) ----------------
template <int K>
__global__ __launch_bounds__(256) void linear_kernel(
    const float* __restrict__ A, const float* __restrict__ W,
    const float* __restrict__ dinv, float* __restrict__ C, int n) {
    __shared__ float As[64][K + 4];
    __shared__ float Ws[K][64];
    int tid = threadIdx.x;
    int tx = tid & 15;
    int ty = tid >> 4;
    int block0 = blockIdx.x * 64;
    int rows = n - block0;
    if (rows > 64) rows = 64;

    const float* Abase = A + (size_t)block0 * K;
    int totalA4 = (rows * K) >> 2;
    for (int i4 = tid; i4 < totalA4; i4 += 256) {
        int i = i4 << 2;
        float4 v = *(const float4*)(Abase + i);
        *(float4*)&As[i / K][i % K] = v;
    }
    {
        const float4* Wv = (const float4*)W;
        float4* Wsv = (float4*)&Ws[0][0];
        for (int i = tid; i < K * 16; i += 256) Wsv[i] = Wv[i];
    }
    __syncthreads();

    float acc[4][4] = {};
#pragma unroll 2
    for (int k = 0; k < K; k += 4) {
        float4 a[4];
#pragma unroll
        for (int i = 0; i < 4; ++i) a[i] = *(const float4*)&As[ty * 4 + i][k];
        float4 w[4];
#pragma unroll
        for (int kk = 0; kk < 4; ++kk) w[kk] = *(const float4*)&Ws[k + kk][tx * 4];
#pragma unroll
        for (int i = 0; i < 4; ++i) {
            float av[4] = {a[i].x, a[i].y, a[i].z, a[i].w};
#pragma unroll
            for (int kk = 0; kk < 4; ++kk) {
                acc[i][0] += av[kk] * w[kk].x;
                acc[i][1] += av[kk] * w[kk].y;
                acc[i][2] += av[kk] * w[kk].z;
                acc[i][3] += av[kk] * w[kk].w;
            }
        }
    }

#pragma unroll
    for (int i = 0; i < 4; ++i) {
        int r = ty * 4 + i;
        if (r < rows) {
            float s = dinv[block0 + r];
            float4 v = {acc[i][0] * s, acc[i][1] * s, acc[i][2] * s, acc[i][3] * s};
            *(float4*)&C[(size_t)(block0 + r) * 64 + tx * 4] = v;
        }
    }
}

// ---------------- per-node float4 gather; fused self-loop+bias+relu ----------------
__global__ __launch_bounds__(256) void gather_kernel(
    const float* __restrict__ hs, const int* __restrict__ rs,
    const int* __restrict__ csr_src, const float* __restrict__ dinv,
    const float* __restrict__ bias, float* __restrict__ outp, int n) {
    int wave = threadIdx.x >> 6;
    int node = blockIdx.x * 4 + wave;
    if (node >= n) return;
    int lane = threadIdx.x & 63;
    int eg = lane >> 4;
    int f4 = (lane & 15) << 2;
    int beg = rs[node], end = rs[node + 1];
    float4 acc = {0.f, 0.f, 0.f, 0.f};
    if (eg == 0) acc = *(const float4*)&hs[(size_t)node * 64 + f4];
    int j = beg + eg;
    for (; j + 4 < end; j += 8) {
        int s0 = csr_src[j];
        int s1 = csr_src[j + 4];
        float4 v0 = *(const float4*)&hs[(size_t)s0 * 64 + f4];
        float4 v1 = *(const float4*)&hs[(size_t)s1 * 64 + f4];
        acc.x += v0.x + v1.x;
        acc.y += v0.y + v1.y;
        acc.z += v0.z + v1.z;
        acc.w += v0.w + v1.w;
    }
    if (j < end) {
        int s = csr_src[j];
        float4 v = *(const float4*)&hs[(size_t)s * 64 + f4];
        acc.x += v.x; acc.y += v.y; acc.z += v.z; acc.w += v.w;
    }
    acc.x += __shfl_xor(acc.x, 16); acc.y += __shfl_xor(acc.y, 16);
    acc.z += __shfl_xor(acc.z, 16); acc.w += __shfl_xor(acc.w, 16);
    acc.x += __shfl_xor(acc.x, 32); acc.y += __shfl_xor(acc.y, 32);
    acc.z += __shfl_xor(acc.z, 32); acc.w += __shfl_xor(acc.w, 32);
    if (eg == 0) {
        float s = dinv[node];
        float4 bb = *(const float4*)&bias[f4];
        float4 o;
        o.x = fmaxf(acc.x * s + bb.x, 0.f);
        o.y = fmaxf(acc.y * s + bb.y, 0.f);
        o.z = fmaxf(acc.z * s + bb.z, 0.f);
        o.w = fmaxf(acc.w * s + bb.w, 0.f);
        *(float4*)&outp[(size_t)node * 64 + f4] = o;
    }
}

// ---------------- fused segmented mean-pool + MLP head ----------------
__device__ __forceinline__ int lower_bound_dev(const int* __restrict__ a, int n, int v) {
    int lo = 0, hi = n;
    while (lo < hi) {
        int m = (lo + hi) >> 1;
        if (a[m] < v) lo = m + 1; else hi = m;
    }
    return lo;
}

__global__ void pool_head_kernel(const float* __restrict__ h, const int* __restrict__ batch,
                                 const float* __restrict__ W1, const float* __restrict__ b1,
                                 const float* __restrict__ W2, const float* __restrict__ b2,
                                 float* __restrict__ out, int nNodes, int nGraphs) {
    __shared__ float p[64];
    __shared__ float t[64];
    int g = blockIdx.x;
    int f = threadIdx.x;  // 64 threads
    int lo = lower_bound_dev(batch, nNodes, g);
    int hi = lower_bound_dev(batch, nNodes, g + 1);
    float sum = 0.0f;
    for (int i = lo; i < hi; ++i) sum += h[i * 64 + f];
    float inv = 1.0f / fmaxf((float)(hi - lo), 1.0f);
    p[f] = sum * inv;
    __syncthreads();
    float acc = b1[f];
#pragma unroll
    for (int k = 0; k < 64; ++k) acc += p[k] * W1[k * 64 + f];
    t[f] = fmaxf(acc, 0.0f);
    __syncthreads();
    if (f < OUT_DIM) {
        float acc2 = b2[f];
#pragma unroll
        for (int k = 0; k < 64; ++k) acc2 += t[k] * W2[k * OUT_DIM + f];
        out[g * OUT_DIM + f] = acc2;
    }
    if (g == 0 && f == 0) out[nGraphs * OUT_DIM] = 0.0f;  // trailing scalar output
}

extern "C" void kernel_launch(void* const* d_in, const int* in_sizes, int n_in,
                              void* d_out, int out_size, void* d_ws, size_t ws_size,
                              hipStream_t stream) {
    const float* x      = (const float*)d_in[0];
    const int*   eidx   = (const int*)d_in[1];
    const int*   batch  = (const int*)d_in[2];
    const float* W1     = (const float*)d_in[3];
    const float* b1     = (const float*)d_in[4];
    const float* W2     = (const float*)d_in[5];
    const float* b2     = (const float*)d_in[6];
    const float* W3     = (const float*)d_in[7];
    const float* b3     = (const float*)d_in[8];
    const float* lin_W1 = (const float*)d_in[9];
    const float* lin_b1 = (const float*)d_in[10];
    const float* lin_W2 = (const float*)d_in[11];
    const float* lin_b2 = (const float*)d_in[12];
    float* out = (float*)d_out;

    const int E = in_sizes[1] / 2;
    const int N = N_NODES;
    const int NF = N * HID;
    const int epb = (E + NBLK - 1) / NBLK;

    const int* src = eidx;
    const int* dst = eidx + E;

    // workspace layout
    float* ws = (float*)d_ws;
    float* buf1 = ws;                   // hs (pre-scaled linear out) [N, 64]
    float* buf2 = buf1 + NF;            // h                          [N, 64]
    float* dinv = buf2 + NF;            // [N]
    int* bhist  = (int*)(dinv + N);     // [NBLK * NB_BUCK]
    int* base   = bhist + NBLK * NB_BUCK;  // [NBLK * NB_BUCK]
    int* bsum   = base + NBLK * NB_BUCK;   // [NB_BUCK]
    int* bstart = bsum + NB_BUCK;          // [NB_BUCK+1]
    int* rs     = bstart + NB_BUCK + 1;    // [N+1]
    int* csr_src = rs + N + 1;             // [E]
    unsigned* pairs = (unsigned*)(csr_src + E);  // [E]

    const int TILES = (N + 63) / 64;  // 782

    // ---- atomic-free edge build ----
    p1_hist_kernel<<<NBLK, 1024, 0, stream>>>(dst, bhist, E, epb);
    scanA_kernel<<<NB_BUCK, 64, 0, stream>>>(bhist, base, bsum);
    bscan_kernel<<<1, 1024, 0, stream>>>(bsum, bstart, NB_BUCK, E);
    p2_place_kernel<<<NBLK, 1024, 0, stream>>>(src, dst, bstart, base, pairs, E, epb);
    csr_scatter2_kernel<<<NB_BUCK, 256, 0, stream>>>(pairs, bstart, rs, dinv, csr_src, N);

    // ---- layer 1 ----
    linear_kernel<IN_DIM><<<TILES, 256, 0, stream>>>(x, W1, dinv, buf1, N);
    gather_kernel<<<(N + 3) / 4, 256, 0, stream>>>(buf1, rs, csr_src, dinv, b1, buf2, N);

    // ---- layer 2 ----
    linear_kernel<HID><<<TILES, 256, 0, stream>>>(buf2, W2, dinv, buf1, N);
    gather_kernel<<<(N + 3) / 4, 256, 0, stream>>>(buf1, rs, csr_src, dinv, b2, buf2, N);

    // ---- layer 3 ----
    linear_kernel<HID><<<TILES, 256, 0, stream>>>(buf2, W3, dinv, buf1, N);
    gather_kernel<<<(N + 3) / 4, 256, 0, stream>>>(buf1, rs, csr_src, dinv, b3, buf2, N);

    // ---- fused pool + head ----
    pool_head_kernel<<<N_GRAPHS, 64, 0, stream>>>(buf2, batch, lin_W1, lin_b1, lin_W2, lin_b2,
                                                  out, N, N_GRAPHS);
}

// Round 10
// 282.921 us; speedup vs baseline: 5.2585x; 1.0930x over previous
//
#include <hip/hip_runtime.h>
#include <hip/hip_bf16.h>

#define N_NODES 50000
#define N_EDGES 800000
#define N_GRAPHS 500
#define IN_DIM 128
#define HID 64
#define OUT_DIM 10
#define NB_BUCK ((N_NODES + 63) >> 6)  // 782 buckets of 64 nodes
#define NBLK 128                       // edge chunks (~6250 edges each)
#define BLDT 512                       // build-kernel block size

// ---------------- P1: per-chunk bucket histogram (LDS, no global atomics) ----------------
__global__ __launch_bounds__(BLDT) void p1_hist_kernel(const int* __restrict__ dst,
                                                       int* __restrict__ bhist, int e, int epb) {
    __shared__ int h[NB_BUCK];
    int tid = threadIdx.x;
    int blk = blockIdx.x;
    for (int i = tid; i < NB_BUCK; i += BLDT) h[i] = 0;
    __syncthreads();
    int e0 = blk * epb;
    int e1 = e0 + epb;
    if (e1 > e) e1 = e;
    for (int i = e0 + tid; i < e1; i += BLDT) atomicAdd(&h[dst[i] >> 6], 1);
    __syncthreads();
    for (int i = tid; i < NB_BUCK; i += BLDT) bhist[blk * NB_BUCK + i] = h[i];
}

// ---- scanA: per bucket, scan NBLK chunk counts IN PLACE (bhist -> exclusive bases) + total ----
__global__ __launch_bounds__(NBLK) void scanA_kernel(int* __restrict__ bhist,
                                                     int* __restrict__ bsum) {
    __shared__ int s[NBLK];
    int b = blockIdx.x;
    int t = threadIdx.x;  // NBLK threads
    int c = bhist[t * NB_BUCK + b];
    s[t] = c;
    __syncthreads();
    for (int off = 1; off < NBLK; off <<= 1) {
        int x = (t >= off) ? s[t - off] : 0;
        __syncthreads();
        s[t] += x;
        __syncthreads();
    }
    bhist[t * NB_BUCK + b] = s[t] - c;  // in-place: now holds exclusive prefix for chunk t
    if (t == NBLK - 1) bsum[b] = s[t];
}

// ---------------- bscan: exclusive scan over bucket totals ----------------
__global__ __launch_bounds__(1024) void bscan_kernel(const int* __restrict__ bsum,
                                                     int* __restrict__ bstart, int nb, int e) {
    __shared__ int s[1024];
    int t = threadIdx.x;
    int v = (t < nb) ? bsum[t] : 0;
    s[t] = v;
    __syncthreads();
    for (int off = 1; off < 1024; off <<= 1) {
        int x = (t >= off) ? s[t - off] : 0;
        __syncthreads();
        s[t] += x;
        __syncthreads();
    }
    if (t < nb) bstart[t] = s[t] - v;
    if (t == 0) bstart[nb] = e;
}

// ---------------- P2: place edges into bucket-grouped pairs (block-local dense segments) ------
__global__ __launch_bounds__(BLDT) void p2_place_kernel(
    const int* __restrict__ src, const int* __restrict__ dst, const int* __restrict__ bstart,
    const int* __restrict__ base, unsigned* __restrict__ pairs, int e, int epb) {
    __shared__ int h[NB_BUCK];   // local rank counters
    __shared__ int sb[NB_BUCK];  // global segment base for this chunk
    int tid = threadIdx.x;
    int blk = blockIdx.x;
    for (int i = tid; i < NB_BUCK; i += BLDT) {
        h[i] = 0;
        sb[i] = bstart[i] + base[blk * NB_BUCK + i];
    }
    __syncthreads();
    int e0 = blk * epb;
    int e1 = e0 + epb;
    if (e1 > e) e1 = e;
    for (int i = e0 + tid; i < e1; i += BLDT) {
        int d = dst[i];
        int b = d >> 6;
        int r = atomicAdd(&h[b], 1);
        pairs[sb[b] + r] = ((unsigned)(d & 63) << 16) | (unsigned)src[i];
    }
}

// ---------------- csr_scatter2: per bucket -> rs, dinv, csr_src (no global atomics) ----------
__global__ __launch_bounds__(256) void csr_scatter2_kernel(
    const unsigned* __restrict__ pairs, const int* __restrict__ bstart,
    int* __restrict__ rs, float* __restrict__ dinv, int* __restrict__ csr_src, int n) {
    __shared__ int lcnt[64];
    __shared__ int lcur[64];
    int b = blockIdx.x;
    int tid = threadIdx.x;
    int beg = bstart[b], end = bstart[b + 1];
    if (tid < 64) lcnt[tid] = 0;
    __syncthreads();
    for (int i = beg + tid; i < end; i += 256) atomicAdd(&lcnt[pairs[i] >> 16], 1);
    __syncthreads();
    if (tid < 64) {  // wave 0: scan the 64 node counts
        int c = lcnt[tid];
        int v = c;
#pragma unroll
        for (int off = 1; off < 64; off <<= 1) {
            int t = __shfl_up(v, off);
            if (tid >= off) v += t;
        }
        int excl = v - c;
        int node = b * 64 + tid;
        if (node <= n) {
            rs[node] = beg + excl;  // node==n lands on rs[N]=E (last bucket's tail)
            if (node < n) dinv[node] = rsqrtf((float)(c + 1));
        }
        lcur[tid] = beg + excl;
    }
    __syncthreads();
    for (int i = beg + tid; i < end; i += 256) {
        unsigned p = pairs[i];
        int slot = atomicAdd(&lcur[p >> 16], 1);
        csr_src[slot] = (int)(p & 0xffffu);
    }
}

// ---------------- tiled linear (+ dinv pre-scale) ----------------
template <int K>
__global__ __launch_bounds__(256) void linear_kernel(
    const float* __restrict__ A, const float* __restrict__ W,
    const float* __restrict__ dinv, float* __restrict__ C, int n) {
    __shared__ float As[64][K + 4];
    __shared__ float Ws[K][64];
    int tid = threadIdx.x;
    int tx = tid & 15;
    int ty = tid >> 4;
    int block0 = blockIdx.x * 64;
    int rows = n - block0;
    if (rows > 64) rows = 64;

    const float* Abase = A + (size_t)block0 * K;
    int totalA4 = (rows * K) >> 2;
    for (int i4 = tid; i4 < totalA4; i4 += 256) {
        int i = i4 << 2;
        float4 v = *(const float4*)(Abase + i);
        *(float4*)&As[i / K][i % K] = v;
    }
    {
        const float4* Wv = (const float4*)W;
        float4* Wsv = (float4*)&Ws[0][0];
        for (int i = tid; i < K * 16; i += 256) Wsv[i] = Wv[i];
    }
    __syncthreads();

    float acc[4][4] = {};
#pragma unroll 2
    for (int k = 0; k < K; k += 4) {
        float4 a[4];
#pragma unroll
        for (int i = 0; i < 4; ++i) a[i] = *(const float4*)&As[ty * 4 + i][k];
        float4 w[4];
#pragma unroll
        for (int kk = 0; kk < 4; ++kk) w[kk] = *(const float4*)&Ws[k + kk][tx * 4];
#pragma unroll
        for (int i = 0; i < 4; ++i) {
            float av[4] = {a[i].x, a[i].y, a[i].z, a[i].w};
#pragma unroll
            for (int kk = 0; kk < 4; ++kk) {
                acc[i][0] += av[kk] * w[kk].x;
                acc[i][1] += av[kk] * w[kk].y;
                acc[i][2] += av[kk] * w[kk].z;
                acc[i][3] += av[kk] * w[kk].w;
            }
        }
    }

#pragma unroll
    for (int i = 0; i < 4; ++i) {
        int r = ty * 4 + i;
        if (r < rows) {
            float s = dinv[block0 + r];
            float4 v = {acc[i][0] * s, acc[i][1] * s, acc[i][2] * s, acc[i][3] * s};
            *(float4*)&C[(size_t)(block0 + r) * 64 + tx * 4] = v;
        }
    }
}

// ---------------- per-node float4 gather, 4 rows in flight; fused self-loop+bias+relu --------
__global__ __launch_bounds__(256) void gather_kernel(
    const float* __restrict__ hs, const int* __restrict__ rs,
    const int* __restrict__ csr_src, const float* __restrict__ dinv,
    const float* __restrict__ bias, float* __restrict__ outp, int n) {
    int wave = threadIdx.x >> 6;
    int node = blockIdx.x * 4 + wave;
    if (node >= n) return;
    int lane = threadIdx.x & 63;
    int eg = lane >> 4;         // edge group 0..3
    int f4 = (lane & 15) << 2;  // feature quad
    int beg = rs[node], end = rs[node + 1];
    float4 acc = {0.f, 0.f, 0.f, 0.f};
    if (eg == 0) acc = *(const float4*)&hs[(size_t)node * 64 + f4];  // self-loop (pre-scaled)
    int j = beg + eg;
    for (; j + 12 < end; j += 16) {  // 4 rows in flight per lane-group
        int s0 = csr_src[j];
        int s1 = csr_src[j + 4];
        int s2 = csr_src[j + 8];
        int s3 = csr_src[j + 12];
        float4 v0 = *(const float4*)&hs[(size_t)s0 * 64 + f4];
        float4 v1 = *(const float4*)&hs[(size_t)s1 * 64 + f4];
        float4 v2 = *(const float4*)&hs[(size_t)s2 * 64 + f4];
        float4 v3 = *(const float4*)&hs[(size_t)s3 * 64 + f4];
        acc.x += v0.x + v1.x + v2.x + v3.x;
        acc.y += v0.y + v1.y + v2.y + v3.y;
        acc.z += v0.z + v1.z + v2.z + v3.z;
        acc.w += v0.w + v1.w + v2.w + v3.w;
    }
    for (; j < end; j += 4) {
        int s = csr_src[j];
        float4 v = *(const float4*)&hs[(size_t)s * 64 + f4];
        acc.x += v.x; acc.y += v.y; acc.z += v.z; acc.w += v.w;
    }
    // merge the 4 edge groups: butterfly over lane bits 4,5
    acc.x += __shfl_xor(acc.x, 16); acc.y += __shfl_xor(acc.y, 16);
    acc.z += __shfl_xor(acc.z, 16); acc.w += __shfl_xor(acc.w, 16);
    acc.x += __shfl_xor(acc.x, 32); acc.y += __shfl_xor(acc.y, 32);
    acc.z += __shfl_xor(acc.z, 32); acc.w += __shfl_xor(acc.w, 32);
    if (eg == 0) {
        float s = dinv[node];
        float4 bb = *(const float4*)&bias[f4];
        float4 o;
        o.x = fmaxf(acc.x * s + bb.x, 0.f);
        o.y = fmaxf(acc.y * s + bb.y, 0.f);
        o.z = fmaxf(acc.z * s + bb.z, 0.f);
        o.w = fmaxf(acc.w * s + bb.w, 0.f);
        *(float4*)&outp[(size_t)node * 64 + f4] = o;
    }
}

// ---------------- fused segmented mean-pool + MLP head (4-wave row-sum) ----------------
__device__ __forceinline__ int lower_bound_dev(const int* __restrict__ a, int n, int v) {
    int lo = 0, hi = n;
    while (lo < hi) {
        int m = (lo + hi) >> 1;
        if (a[m] < v) lo = m + 1; else hi = m;
    }
    return lo;
}

__global__ __launch_bounds__(256) void pool_head_kernel(
    const float* __restrict__ h, const int* __restrict__ batch,
    const float* __restrict__ W1, const float* __restrict__ b1,
    const float* __restrict__ W2, const float* __restrict__ b2,
    float* __restrict__ out, int nNodes, int nGraphs) {
    __shared__ float psum[4][64];
    __shared__ float p[64];
    __shared__ float t64[64];
    int g = blockIdx.x;
    int tid = threadIdx.x;
    int f = tid & 63;
    int q = tid >> 6;  // wave id 0..3
    int lo = lower_bound_dev(batch, nNodes, g);
    int hi = lower_bound_dev(batch, nNodes, g + 1);
    float sum = 0.0f;
    for (int i = lo + q; i < hi; i += 4) sum += h[(size_t)i * 64 + f];
    psum[q][f] = sum;
    __syncthreads();
    if (tid < 64) {  // wave 0 only; intra-wave lockstep -> no barriers needed below
        float s = psum[0][f] + psum[1][f] + psum[2][f] + psum[3][f];
        float inv = 1.0f / fmaxf((float)(hi - lo), 1.0f);
        p[f] = s * inv;
        float acc = b1[f];
#pragma unroll
        for (int k = 0; k < 64; ++k) acc += p[k] * W1[k * 64 + f];
        t64[f] = fmaxf(acc, 0.0f);
        if (f < OUT_DIM) {
            float acc2 = b2[f];
#pragma unroll
            for (int k = 0; k < 64; ++k) acc2 += t64[k] * W2[k * OUT_DIM + f];
            out[g * OUT_DIM + f] = acc2;
        }
        if (g == 0 && f == 0) out[nGraphs * OUT_DIM] = 0.0f;  // trailing scalar output
    }
}

extern "C" void kernel_launch(void* const* d_in, const int* in_sizes, int n_in,
                              void* d_out, int out_size, void* d_ws, size_t ws_size,
                              hipStream_t stream) {
    const float* x      = (const float*)d_in[0];
    const int*   eidx   = (const int*)d_in[1];
    const int*   batch  = (const int*)d_in[2];
    const float* W1     = (const float*)d_in[3];
    const float* b1     = (const float*)d_in[4];
    const float* W2     = (const float*)d_in[5];
    const float* b2     = (const float*)d_in[6];
    const float* W3     = (const float*)d_in[7];
    const float* b3     = (const float*)d_in[8];
    const float* lin_W1 = (const float*)d_in[9];
    const float* lin_b1 = (const float*)d_in[10];
    const float* lin_W2 = (const float*)d_in[11];
    const float* lin_b2 = (const float*)d_in[12];
    float* out = (float*)d_out;

    const int E = in_sizes[1] / 2;
    const int N = N_NODES;
    const int NF = N * HID;
    const int epb = (E + NBLK - 1) / NBLK;

    const int* src = eidx;
    const int* dst = eidx + E;

    // workspace layout
    float* ws = (float*)d_ws;
    float* buf1 = ws;                   // hs (pre-scaled linear out) [N, 64]
    float* buf2 = buf1 + NF;            // h                          [N, 64]
    float* dinv = buf2 + NF;            // [N]
    int* bhist  = (int*)(dinv + N);     // [NBLK * NB_BUCK]  (in-place: counts -> bases)
    int* bsum   = bhist + NBLK * NB_BUCK;  // [NB_BUCK]
    int* bstart = bsum + NB_BUCK;          // [NB_BUCK+1]
    int* rs     = bstart + NB_BUCK + 1;    // [N+1]
    int* csr_src = rs + N + 1;             // [E]
    unsigned* pairs = (unsigned*)(csr_src + E);  // [E]

    const int TILES = (N + 63) / 64;  // 782

    // ---- atomic-free edge build ----
    p1_hist_kernel<<<NBLK, BLDT, 0, stream>>>(dst, bhist, E, epb);
    scanA_kernel<<<NB_BUCK, NBLK, 0, stream>>>(bhist, bsum);
    bscan_kernel<<<1, 1024, 0, stream>>>(bsum, bstart, NB_BUCK, E);
    p2_place_kernel<<<NBLK, BLDT, 0, stream>>>(src, dst, bstart, bhist, pairs, E, epb);
    csr_scatter2_kernel<<<NB_BUCK, 256, 0, stream>>>(pairs, bstart, rs, dinv, csr_src, N);

    // ---- layer 1 ----
    linear_kernel<IN_DIM><<<TILES, 256, 0, stream>>>(x, W1, dinv, buf1, N);
    gather_kernel<<<(N + 3) / 4, 256, 0, stream>>>(buf1, rs, csr_src, dinv, b1, buf2, N);

    // ---- layer 2 ----
    linear_kernel<HID><<<TILES, 256, 0, stream>>>(buf2, W2, dinv, buf1, N);
    gather_kernel<<<(N + 3) / 4, 256, 0, stream>>>(buf1, rs, csr_src, dinv, b2, buf2, N);

    // ---- layer 3 ----
    linear_kernel<HID><<<TILES, 256, 0, stream>>>(buf2, W3, dinv, buf1, N);
    gather_kernel<<<(N + 3) / 4, 256, 0, stream>>>(buf1, rs, csr_src, dinv, b3, buf2, N);

    // ---- fused pool + head ----
    pool_head_kernel<<<N_GRAPHS, 256, 0, stream>>>(buf2, batch, lin_W1, lin_b1, lin_W2, lin_b2,
                                                   out, N, N_GRAPHS);
}

// Round 11
// 265.706 us; speedup vs baseline: 5.5992x; 1.0648x over previous
//
#include <hip/hip_runtime.h>
#include <hip/hip_bf16.h>

#define N_NODES 50000
#define N_EDGES 800000
#define N_GRAPHS 500
#define IN_DIM 128
#define HID 64
#define OUT_DIM 10
#define NB_BUCK ((N_NODES + 63) >> 6)  // 782 buckets of 64 nodes
#define NBLK 128                       // edge chunks (~6250 edges each)
#define BLDT 512                       // build-kernel block size

// ---- bf16 helpers: exact expand on load, RNE on store ----
__device__ __forceinline__ float bf2f(unsigned short u) {
    return __uint_as_float(((unsigned)u) << 16);
}
__device__ __forceinline__ unsigned short f2bf(float f) {
    unsigned x = __float_as_uint(f);
    x += 0x7fffu + ((x >> 16) & 1u);  // round-to-nearest-even
    return (unsigned short)(x >> 16);
}

// ---------------- P1: per-chunk bucket histogram (LDS, no global atomics) ----------------
__global__ __launch_bounds__(BLDT) void p1_hist_kernel(const int* __restrict__ dst,
                                                       int* __restrict__ bhist, int e, int epb) {
    __shared__ int h[NB_BUCK];
    int tid = threadIdx.x;
    int blk = blockIdx.x;
    for (int i = tid; i < NB_BUCK; i += BLDT) h[i] = 0;
    __syncthreads();
    int e0 = blk * epb;
    int e1 = e0 + epb;
    if (e1 > e) e1 = e;
    for (int i = e0 + tid; i < e1; i += BLDT) atomicAdd(&h[dst[i] >> 6], 1);
    __syncthreads();
    for (int i = tid; i < NB_BUCK; i += BLDT) bhist[blk * NB_BUCK + i] = h[i];
}

// ---- scanA: per bucket, scan NBLK chunk counts IN PLACE (bhist -> exclusive bases) + total ----
__global__ __launch_bounds__(NBLK) void scanA_kernel(int* __restrict__ bhist,
                                                     int* __restrict__ bsum) {
    __shared__ int s[NBLK];
    int b = blockIdx.x;
    int t = threadIdx.x;  // NBLK threads
    int c = bhist[t * NB_BUCK + b];
    s[t] = c;
    __syncthreads();
    for (int off = 1; off < NBLK; off <<= 1) {
        int x = (t >= off) ? s[t - off] : 0;
        __syncthreads();
        s[t] += x;
        __syncthreads();
    }
    bhist[t * NB_BUCK + b] = s[t] - c;  // in-place: exclusive prefix for chunk t
    if (t == NBLK - 1) bsum[b] = s[t];
}

// ---------------- bscan: exclusive scan over bucket totals ----------------
__global__ __launch_bounds__(1024) void bscan_kernel(const int* __restrict__ bsum,
                                                     int* __restrict__ bstart, int nb, int e) {
    __shared__ int s[1024];
    int t = threadIdx.x;
    int v = (t < nb) ? bsum[t] : 0;
    s[t] = v;
    __syncthreads();
    for (int off = 1; off < 1024; off <<= 1) {
        int x = (t >= off) ? s[t - off] : 0;
        __syncthreads();
        s[t] += x;
        __syncthreads();
    }
    if (t < nb) bstart[t] = s[t] - v;
    if (t == 0) bstart[nb] = e;
}

// ---------------- P2: place edges into bucket-grouped pairs (block-local dense segments) ------
__global__ __launch_bounds__(BLDT) void p2_place_kernel(
    const int* __restrict__ src, const int* __restrict__ dst, const int* __restrict__ bstart,
    const int* __restrict__ base, unsigned* __restrict__ pairs, int e, int epb) {
    __shared__ int h[NB_BUCK];   // local rank counters
    __shared__ int sb[NB_BUCK];  // global segment base for this chunk
    int tid = threadIdx.x;
    int blk = blockIdx.x;
    for (int i = tid; i < NB_BUCK; i += BLDT) {
        h[i] = 0;
        sb[i] = bstart[i] + base[blk * NB_BUCK + i];
    }
    __syncthreads();
    int e0 = blk * epb;
    int e1 = e0 + epb;
    if (e1 > e) e1 = e;
    for (int i = e0 + tid; i < e1; i += BLDT) {
        int d = dst[i];
        int b = d >> 6;
        int r = atomicAdd(&h[b], 1);
        pairs[sb[b] + r] = ((unsigned)(d & 63) << 16) | (unsigned)src[i];
    }
}

// ---------------- csr_scatter2: per bucket -> rs, dinv, csr_src (no global atomics) ----------
__global__ __launch_bounds__(256) void csr_scatter2_kernel(
    const unsigned* __restrict__ pairs, const int* __restrict__ bstart,
    int* __restrict__ rs, float* __restrict__ dinv, int* __restrict__ csr_src, int n) {
    __shared__ int lcnt[64];
    __shared__ int lcur[64];
    int b = blockIdx.x;
    int tid = threadIdx.x;
    int beg = bstart[b], end = bstart[b + 1];
    if (tid < 64) lcnt[tid] = 0;
    __syncthreads();
    for (int i = beg + tid; i < end; i += 256) atomicAdd(&lcnt[pairs[i] >> 16], 1);
    __syncthreads();
    if (tid < 64) {  // wave 0: scan the 64 node counts
        int c = lcnt[tid];
        int v = c;
#pragma unroll
        for (int off = 1; off < 64; off <<= 1) {
            int t = __shfl_up(v, off);
            if (tid >= off) v += t;
        }
        int excl = v - c;
        int node = b * 64 + tid;
        if (node <= n) {
            rs[node] = beg + excl;  // node==n lands on rs[N]=E (last bucket's tail)
            if (node < n) dinv[node] = rsqrtf((float)(c + 1));
        }
        lcur[tid] = beg + excl;
    }
    __syncthreads();
    for (int i = beg + tid; i < end; i += 256) {
        unsigned p = pairs[i];
        int slot = atomicAdd(&lcur[p >> 16], 1);
        csr_src[slot] = (int)(p & 0xffffu);
    }
}

// ---------------- layer-1 linear: fp32 A (K=128) -> bf16 hs (+ dinv pre-scale) ----------------
__global__ __launch_bounds__(256) void linear1_kernel(
    const float* __restrict__ A, const float* __restrict__ W,
    const float* __restrict__ dinv, unsigned short* __restrict__ C, int n) {
    const int K = IN_DIM;
    __shared__ float As[64][K + 4];
    __shared__ float Ws[K][64];
    int tid = threadIdx.x;
    int tx = tid & 15;
    int ty = tid >> 4;
    int block0 = blockIdx.x * 64;
    int rows = n - block0;
    if (rows > 64) rows = 64;

    const float* Abase = A + (size_t)block0 * K;
    int totalA4 = (rows * K) >> 2;
    for (int i4 = tid; i4 < totalA4; i4 += 256) {
        int i = i4 << 2;
        float4 v = *(const float4*)(Abase + i);
        *(float4*)&As[i / K][i % K] = v;
    }
    {
        const float4* Wv = (const float4*)W;
        float4* Wsv = (float4*)&Ws[0][0];
        for (int i = tid; i < K * 16; i += 256) Wsv[i] = Wv[i];
    }
    __syncthreads();

    float acc[4][4] = {};
#pragma unroll 2
    for (int k = 0; k < K; k += 4) {
        float4 a[4];
#pragma unroll
        for (int i = 0; i < 4; ++i) a[i] = *(const float4*)&As[ty * 4 + i][k];
        float4 w[4];
#pragma unroll
        for (int kk = 0; kk < 4; ++kk) w[kk] = *(const float4*)&Ws[k + kk][tx * 4];
#pragma unroll
        for (int i = 0; i < 4; ++i) {
            float av[4] = {a[i].x, a[i].y, a[i].z, a[i].w};
#pragma unroll
            for (int kk = 0; kk < 4; ++kk) {
                acc[i][0] += av[kk] * w[kk].x;
                acc[i][1] += av[kk] * w[kk].y;
                acc[i][2] += av[kk] * w[kk].z;
                acc[i][3] += av[kk] * w[kk].w;
            }
        }
    }

#pragma unroll
    for (int i = 0; i < 4; ++i) {
        int r = ty * 4 + i;
        if (r < rows) {
            float s = dinv[block0 + r];
            ushort4 v;
            v.x = f2bf(acc[i][0] * s);
            v.y = f2bf(acc[i][1] * s);
            v.z = f2bf(acc[i][2] * s);
            v.w = f2bf(acc[i][3] * s);
            *(ushort4*)&C[(size_t)(block0 + r) * 64 + tx * 4] = v;
        }
    }
}

// ---------------- layers-2/3 linear: bf16 A (K=64) -> bf16 hs (+ dinv pre-scale) --------------
__global__ __launch_bounds__(256) void linear_bf_kernel(
    const unsigned short* __restrict__ A, const float* __restrict__ W,
    const float* __restrict__ dinv, unsigned short* __restrict__ C, int n) {
    const int K = HID;
    __shared__ float As[64][K + 4];
    __shared__ float Ws[K][64];
    int tid = threadIdx.x;
    int tx = tid & 15;
    int ty = tid >> 4;
    int block0 = blockIdx.x * 64;
    int rows = n - block0;
    if (rows > 64) rows = 64;

    const unsigned short* Abase = A + (size_t)block0 * K;
    int total8 = rows * 8;  // 16B (8 bf16) units
    for (int u = tid; u < total8; u += 256) {
        int r = u >> 3;
        int c8 = (u & 7) << 3;
        uint4 raw = *(const uint4*)(Abase + (size_t)r * K + c8);
        float4 a0, a1;
        a0.x = __uint_as_float(raw.x << 16);
        a0.y = __uint_as_float(raw.x & 0xffff0000u);
        a0.z = __uint_as_float(raw.y << 16);
        a0.w = __uint_as_float(raw.y & 0xffff0000u);
        a1.x = __uint_as_float(raw.z << 16);
        a1.y = __uint_as_float(raw.z & 0xffff0000u);
        a1.z = __uint_as_float(raw.w << 16);
        a1.w = __uint_as_float(raw.w & 0xffff0000u);
        *(float4*)&As[r][c8] = a0;
        *(float4*)&As[r][c8 + 4] = a1;
    }
    {
        const float4* Wv = (const float4*)W;
        float4* Wsv = (float4*)&Ws[0][0];
        for (int i = tid; i < K * 16; i += 256) Wsv[i] = Wv[i];
    }
    __syncthreads();

    float acc[4][4] = {};
#pragma unroll 2
    for (int k = 0; k < K; k += 4) {
        float4 a[4];
#pragma unroll
        for (int i = 0; i < 4; ++i) a[i] = *(const float4*)&As[ty * 4 + i][k];
        float4 w[4];
#pragma unroll
        for (int kk = 0; kk < 4; ++kk) w[kk] = *(const float4*)&Ws[k + kk][tx * 4];
#pragma unroll
        for (int i = 0; i < 4; ++i) {
            float av[4] = {a[i].x, a[i].y, a[i].z, a[i].w};
#pragma unroll
            for (int kk = 0; kk < 4; ++kk) {
                acc[i][0] += av[kk] * w[kk].x;
                acc[i][1] += av[kk] * w[kk].y;
                acc[i][2] += av[kk] * w[kk].z;
                acc[i][3] += av[kk] * w[kk].w;
            }
        }
    }

#pragma unroll
    for (int i = 0; i < 4; ++i) {
        int r = ty * 4 + i;
        if (r < rows) {
            float s = dinv[block0 + r];
            ushort4 v;
            v.x = f2bf(acc[i][0] * s);
            v.y = f2bf(acc[i][1] * s);
            v.z = f2bf(acc[i][2] * s);
            v.w = f2bf(acc[i][3] * s);
            *(ushort4*)&C[(size_t)(block0 + r) * 64 + tx * 4] = v;
        }
    }
}

// ------- per-node bf16 gather, 4 rows in flight, fp32 accumulate; fused self-loop+bias+relu ---
__global__ __launch_bounds__(256) void gather_kernel(
    const unsigned short* __restrict__ hs, const int* __restrict__ rs,
    const int* __restrict__ csr_src, const float* __restrict__ dinv,
    const float* __restrict__ bias, unsigned short* __restrict__ outp, int n) {
    int wave = threadIdx.x >> 6;
    int node = blockIdx.x * 4 + wave;
    if (node >= n) return;
    int lane = threadIdx.x & 63;
    int eg = lane >> 4;         // edge group 0..3
    int f4 = (lane & 15) << 2;  // feature quad
    int beg = rs[node], end = rs[node + 1];
    float4 acc = {0.f, 0.f, 0.f, 0.f};
    if (eg == 0) {  // self-loop (pre-scaled)
        ushort4 u = *(const ushort4*)&hs[(size_t)node * 64 + f4];
        acc.x = bf2f(u.x); acc.y = bf2f(u.y); acc.z = bf2f(u.z); acc.w = bf2f(u.w);
    }
    int j = beg + eg;
    for (; j + 12 < end; j += 16) {  // 4 rows in flight per lane-group
        int s0 = csr_src[j];
        int s1 = csr_src[j + 4];
        int s2 = csr_src[j + 8];
        int s3 = csr_src[j + 12];
        ushort4 u0 = *(const ushort4*)&hs[(size_t)s0 * 64 + f4];
        ushort4 u1 = *(const ushort4*)&hs[(size_t)s1 * 64 + f4];
        ushort4 u2 = *(const ushort4*)&hs[(size_t)s2 * 64 + f4];
        ushort4 u3 = *(const ushort4*)&hs[(size_t)s3 * 64 + f4];
        acc.x += bf2f(u0.x) + bf2f(u1.x) + bf2f(u2.x) + bf2f(u3.x);
        acc.y += bf2f(u0.y) + bf2f(u1.y) + bf2f(u2.y) + bf2f(u3.y);
        acc.z += bf2f(u0.z) + bf2f(u1.z) + bf2f(u2.z) + bf2f(u3.z);
        acc.w += bf2f(u0.w) + bf2f(u1.w) + bf2f(u2.w) + bf2f(u3.w);
    }
    for (; j < end; j += 4) {
        int s = csr_src[j];
        ushort4 u = *(const ushort4*)&hs[(size_t)s * 64 + f4];
        acc.x += bf2f(u.x); acc.y += bf2f(u.y); acc.z += bf2f(u.z); acc.w += bf2f(u.w);
    }
    // merge the 4 edge groups: butterfly over lane bits 4,5
    acc.x += __shfl_xor(acc.x, 16); acc.y += __shfl_xor(acc.y, 16);
    acc.z += __shfl_xor(acc.z, 16); acc.w += __shfl_xor(acc.w, 16);
    acc.x += __shfl_xor(acc.x, 32); acc.y += __shfl_xor(acc.y, 32);
    acc.z += __shfl_xor(acc.z, 32); acc.w += __shfl_xor(acc.w, 32);
    if (eg == 0) {
        float s = dinv[node];
        float4 bb = *(const float4*)&bias[f4];
        ushort4 o;
        o.x = f2bf(fmaxf(acc.x * s + bb.x, 0.f));
        o.y = f2bf(fmaxf(acc.y * s + bb.y, 0.f));
        o.z = f2bf(fmaxf(acc.z * s + bb.z, 0.f));
        o.w = f2bf(fmaxf(acc.w * s + bb.w, 0.f));
        *(ushort4*)&outp[(size_t)node * 64 + f4] = o;
    }
}

// ---------------- fused segmented mean-pool + MLP head (4-wave row-sum, bf16 in) -------------
__device__ __forceinline__ int lower_bound_dev(const int* __restrict__ a, int n, int v) {
    int lo = 0, hi = n;
    while (lo < hi) {
        int m = (lo + hi) >> 1;
        if (a[m] < v) lo = m + 1; else hi = m;
    }
    return lo;
}

__global__ __launch_bounds__(256) void pool_head_kernel(
    const unsigned short* __restrict__ h, const int* __restrict__ batch,
    const float* __restrict__ W1, const float* __restrict__ b1,
    const float* __restrict__ W2, const float* __restrict__ b2,
    float* __restrict__ out, int nNodes, int nGraphs) {
    __shared__ float psum[4][64];
    __shared__ float p[64];
    __shared__ float t64[64];
    int g = blockIdx.x;
    int tid = threadIdx.x;
    int f = tid & 63;
    int q = tid >> 6;  // wave id 0..3
    int lo = lower_bound_dev(batch, nNodes, g);
    int hi = lower_bound_dev(batch, nNodes, g + 1);
    float sum = 0.0f;
    for (int i = lo + q; i < hi; i += 4) sum += bf2f(h[(size_t)i * 64 + f]);
    psum[q][f] = sum;
    __syncthreads();
    if (tid < 64) {  // wave 0 only; intra-wave lockstep below
        float s = psum[0][f] + psum[1][f] + psum[2][f] + psum[3][f];
        float inv = 1.0f / fmaxf((float)(hi - lo), 1.0f);
        p[f] = s * inv;
        float acc = b1[f];
#pragma unroll
        for (int k = 0; k < 64; ++k) acc += p[k] * W1[k * 64 + f];
        t64[f] = fmaxf(acc, 0.0f);
        if (f < OUT_DIM) {
            float acc2 = b2[f];
#pragma unroll
            for (int k = 0; k < 64; ++k) acc2 += t64[k] * W2[k * OUT_DIM + f];
            out[g * OUT_DIM + f] = acc2;
        }
        if (g == 0 && f == 0) out[nGraphs * OUT_DIM] = 0.0f;  // trailing scalar output
    }
}

extern "C" void kernel_launch(void* const* d_in, const int* in_sizes, int n_in,
                              void* d_out, int out_size, void* d_ws, size_t ws_size,
                              hipStream_t stream) {
    const float* x      = (const float*)d_in[0];
    const int*   eidx   = (const int*)d_in[1];
    const int*   batch  = (const int*)d_in[2];
    const float* W1     = (const float*)d_in[3];
    const float* b1     = (const float*)d_in[4];
    const float* W2     = (const float*)d_in[5];
    const float* b2     = (const float*)d_in[6];
    const float* W3     = (const float*)d_in[7];
    const float* b3     = (const float*)d_in[8];
    const float* lin_W1 = (const float*)d_in[9];
    const float* lin_b1 = (const float*)d_in[10];
    const float* lin_W2 = (const float*)d_in[11];
    const float* lin_b2 = (const float*)d_in[12];
    float* out = (float*)d_out;

    const int E = in_sizes[1] / 2;
    const int N = N_NODES;
    const int NF = N * HID;
    const int epb = (E + NBLK - 1) / NBLK;

    const int* src = eidx;
    const int* dst = eidx + E;

    // workspace layout
    unsigned short* buf1 = (unsigned short*)d_ws;  // hs bf16 [N,64]
    unsigned short* buf2 = buf1 + NF;              // h  bf16 [N,64]
    float* dinv = (float*)(buf2 + NF);             // [N]
    int* bhist  = (int*)(dinv + N);                // [NBLK * NB_BUCK] (in-place counts->bases)
    int* bsum   = bhist + NBLK * NB_BUCK;          // [NB_BUCK]
    int* bstart = bsum + NB_BUCK;                  // [NB_BUCK+1]
    int* rs     = bstart + NB_BUCK + 1;            // [N+1]
    int* csr_src = rs + N + 1;                     // [E]
    unsigned* pairs = (unsigned*)(csr_src + E);    // [E]

    const int TILES = (N + 63) / 64;  // 782

    // ---- atomic-free edge build ----
    p1_hist_kernel<<<NBLK, BLDT, 0, stream>>>(dst, bhist, E, epb);
    scanA_kernel<<<NB_BUCK, NBLK, 0, stream>>>(bhist, bsum);
    bscan_kernel<<<1, 1024, 0, stream>>>(bsum, bstart, NB_BUCK, E);
    p2_place_kernel<<<NBLK, BLDT, 0, stream>>>(src, dst, bstart, bhist, pairs, E, epb);
    csr_scatter2_kernel<<<NB_BUCK, 256, 0, stream>>>(pairs, bstart, rs, dinv, csr_src, N);

    // ---- layer 1 ----
    linear1_kernel<<<TILES, 256, 0, stream>>>(x, W1, dinv, buf1, N);
    gather_kernel<<<(N + 3) / 4, 256, 0, stream>>>(buf1, rs, csr_src, dinv, b1, buf2, N);

    // ---- layer 2 ----
    linear_bf_kernel<<<TILES, 256, 0, stream>>>(buf2, W2, dinv, buf1, N);
    gather_kernel<<<(N + 3) / 4, 256, 0, stream>>>(buf1, rs, csr_src, dinv, b2, buf2, N);

    // ---- layer 3 ----
    linear_bf_kernel<<<TILES, 256, 0, stream>>>(buf2, W3, dinv, buf1, N);
    gather_kernel<<<(N + 3) / 4, 256, 0, stream>>>(buf1, rs, csr_src, dinv, b3, buf2, N);

    // ---- fused pool + head ----
    pool_head_kernel<<<N_GRAPHS, 256, 0, stream>>>(buf2, batch, lin_W1, lin_b1, lin_W2, lin_b2,
                                                   out, N, N_GRAPHS);
}